// Round 9
// baseline (594.733 us; speedup 1.0000x reference)
//
#include <hip/hip_runtime.h>
#include <cmath>

typedef unsigned long long u64;

namespace {
constexpr int kNZ = 300, kNX = 400;
constexpr int kNPML = 32;
constexpr int kNZP = 364, kNXP = 464;        // padded physical grid
constexpr int kNSTEPS = 200, kNSHOTS = 2;
constexpr int kSRC_Z = 34, kREC_Z = 34;      // NPML + 2
constexpr float kDT = 0.001f;
constexpr float kINV_DX = 100.0f;            // 1/DX

// r26 = r25 (488us WIN: 8-row slabs, two parallel 512-thread row groups,
// 45-link chain) + two tail shavings:
//  (1) group-local LDS-vote flag publish (flag departs at the publishing
//      group's last per-wave drain, not after the global barrier),
//  (2) pre-vel split around the spin (1 row hides part of halo-load RTT).
constexpr int kRS = 8;                        // rows per slab
constexpr int kQ  = 4;                        // rows per thread (per group)
constexpr int kNSLAB = 46;                    // 368 rows; 364..367 dead (zero moduli)
constexpr int kNB = kNSLAB - 1;               // 45 boundaries
constexpr int kBlocks = kNSHOTS * kNSLAB;     // 92 blocks, co-resident
constexpr int kThreads = 1024;                // 2 groups x 512 (464 cols active)
constexpr int kPitch = 468;                   // LDS row pitch (guard cols 0,465)
constexpr int kFStride = kRS * kPitch;        // 3744

// ws layout — NO init kernel needed (round-0 protocol, kNB=45):
//   [0, 16384)   : int flags[shot][b][dir] x32 pad. 0xAA poison = negative int
//                  => every signed `< t` wait is safe un-zeroed.
//   [16384, ...) : float halo[buf][shot][b][dir][slot(6)][464]
//   partials     : 2 x u64 {tag,float} at 8-aligned offset after halos.
constexpr int kFlagStride = 32;
constexpr int kHaloBase = 16384;
constexpr int kHaloCount = 2 * kNSHOTS * kNB * 2 * 6 * kNXP;   // 1,002,240
constexpr int kPartOff = kHaloBase + kHaloCount;               // even -> 8B aligned
}  // namespace

#define ALD(p)    __hip_atomic_load((p),       __ATOMIC_RELAXED, __HIP_MEMORY_SCOPE_AGENT)
#define AST(p, v) __hip_atomic_store((p), (v), __ATOMIC_RELAXED, __HIP_MEMORY_SCOPE_AGENT)
// LDS-ordering-only barrier (no vmcnt drain) — proven safe r18/r21/r22.
#define LDS_BAR() asm volatile("s_waitcnt lgkmcnt(0)\n\ts_barrier" ::: "memory")

// Per-step schedule, protocol and FP expressions are r25's verbatim; only
// the flag-publish path and pre-vel placement changed.
__global__ __launch_bounds__(kThreads, 1) void fwi_sim_kernel(
    const float* __restrict__ Vp, const float* __restrict__ Vs,
    const float* __restrict__ Den, const float* __restrict__ Stf,
    const int* __restrict__ Shot_ids, float* __restrict__ ws,
    float* __restrict__ out) {
    __shared__ float L[5 * kFStride];   // 74,880 B (vx,vz,sxx,sxz,szz)
    __shared__ int cnt[2];              // monotonic per-group drain counters
    float* Lvx  = L;
    float* Lvz  = L + kFStride;
    float* Lsxx = L + 2 * kFStride;
    float* Lsxz = L + 3 * kFStride;
    float* Lszz = L + 4 * kFStride;

    const int blk  = blockIdx.x;
    const int s    = blk / kNSLAB;
    const int slab = blk - s * kNSLAB;
    const int tid  = threadIdx.x;
    const int g    = tid >> 9;          // row-group: 0 = rows 0..3, 1 = rows 4..7
    const int ct   = tid & 511;         // column thread within group
    const bool active = ct < kNXP;
    const int lc = ct + 1;
    const int e0 = 4 * g;               // first row-in-slab of this group
    const int r0 = slab * kRS + e0;     // first global row of this thread

    int*   flags = (int*)ws;
    float* halo  = ws + kHaloBase;
    u64*   part  = (u64*)(ws + kPartOff);

    for (int q = tid; q < 5 * kFStride; q += kThreads) L[q] = 0.0f;
    if (tid < 2) cnt[tid] = 0;

    auto modAt = [&](int i, int j, float& dtr_, float& dmp_, float& lam_,
                     float& mu_, float& l2m_) {
        dtr_ = dmp_ = lam_ = mu_ = l2m_ = 0.0f;
        if (i >= 0 && i < kNZP && j >= 0 && j < kNXP) {
            int iz = i - kNPML; iz = iz < 0 ? 0 : (iz > kNZ - 1 ? kNZ - 1 : iz);
            int jx = j - kNPML; jx = jx < 0 ? 0 : (jx > kNX - 1 ? kNX - 1 : jx);
            const float vp  = Vp[iz * kNX + jx];
            const float vs  = Vs[iz * kNX + jx];
            const float rho = Den[iz * kNX + jx];
            const float m = vs * vs * rho * 1e-6f;
            const float l = (vp * vp - 2.0f * vs * vs) * rho * 1e-6f;
            const float sc = kDT * kINV_DX;
            float dz = fmaxf((float)(kNPML - i), (float)(i - (kNZP - 1 - kNPML)));
            dz = fminf(fmaxf(dz, 0.0f), (float)kNPML) * (1.0f / kNPML);
            float dxx = fmaxf((float)(kNPML - j), (float)(j - (kNXP - 1 - kNPML)));
            dxx = fminf(fmaxf(dxx, 0.0f), (float)kNPML) * (1.0f / kNPML);
            dmp_ = expf(-0.1f * (dz * dz + dxx * dxx));
            dtr_ = kDT / rho * kINV_DX;
            lam_ = l * sc;
            mu_  = m * sc;
            l2m_ = (l + 2.0f * m) * sc;
        }
    };
    float rdtr[kQ], rdamp[kQ], rlam[kQ], rmu[kQ], rl2m[kQ];
    float dtrG = 0, dmpG = 0;            // g0: row slab*8-1 (top ghost); g1: +8 (bottom)
    if (active) {
#pragma unroll
        for (int q = 0; q < kQ; ++q)
            modAt(r0 + q, ct, rdtr[q], rdamp[q], rlam[q], rmu[q], rl2m[q]);
        float d0, d1, d2;
        if (g == 0) modAt(slab * kRS - 1,   ct, dtrG, dmpG, d0, d1, d2);
        else        modAt(slab * kRS + kRS, ct, dtrG, dmpG, d0, d1, d2);
    }

    const int id  = Shot_ids[s];
    const int sxp = kNPML + 20 + id * ((kNX - 40) / kNSHOTS);
    const float* stf = Stf + id * kNSTEPS;
    const int qsrc = kSRC_Z - r0;       // in [0,4) only for the owning group
    const int qrec = kREC_Z - r0;
    const bool isRecBlock = (kREC_Z >= slab * kRS && kREC_Z < slab * kRS + kRS);
    const float srcm = (active && ct == sxp) ? 1.0f : 0.0f;
    const float recm = (active && (unsigned)(ct - kNPML) < (unsigned)kNX) ? 1.0f : 0.0f;

    const bool hasTop = (slab > 0);
    const bool hasBot = (slab < kNSLAB - 1);
    int* ftopw = hasTop ? &flags[((s * kNB + (slab - 1)) * 2 + 1) * kFlagStride] : nullptr;
    int* fbotw = hasBot ? &flags[((s * kNB + slab) * 2 + 0) * kFlagStride] : nullptr;
    int* ftopr = hasTop ? &flags[((s * kNB + (slab - 1)) * 2 + 0) * kFlagStride] : nullptr;
    int* fbotr = hasBot ? &flags[((s * kNB + slab) * 2 + 1) * kFlagStride] : nullptr;
    auto hbase = [&](int buf, int b, int dir) {
        return halo + ((((buf * kNSHOTS + s) * kNB + b) * 2 + dir) * 6) * kNXP;
    };

    float fvx[kQ]  = {}, fvz[kQ]  = {}, fsxx[kQ] = {}, fszz[kQ] = {}, fsxz[kQ] = {};
    float rsum = 0.0f;

    // velocity row update (round-0 expressions; vertical neighbors passed in)
    auto velRow = [&](int q, float sxz_up, float szz_dn) {
        const int E = e0 + q;
        const float sxxC = fsxx[q], sxzC = fsxz[q], szzC = fszz[q];
        const float sxxR = Lsxx[E * kPitch + lc + 1];
        const float sxzL = Lsxz[E * kPitch + lc - 1];
        const float nvx = (fvx[q] + rdtr[q] * ((sxxR - sxxC) + (sxzC - sxz_up))) * rdamp[q];
        const float nvz = (fvz[q] + rdtr[q] * ((sxzC - sxzL) + (szz_dn - szzC))) * rdamp[q];
        fvx[q] = nvx; fvz[q] = nvz;
        Lvx[E * kPitch + lc] = nvx; Lvz[E * kPitch + lc] = nvz;
        if (q == qrec) rsum += recm * nvx * nvx;
    };
    // stress row update (round-0 expressions)
    auto stressRow = [&](int q, float vzU, float vxD, float sval) {
        const int E = e0 + q;
        const float vxC = fvx[q], vzC = fvz[q];
        const float vxL = Lvx[E * kPitch + lc - 1];
        const float vzR = Lvz[E * kPitch + lc + 1];
        const float dvx = vxC - vxL;
        const float dvz = vzC - vzU;
        float nsxx = (fsxx[q] + (rl2m[q] * dvx + rlam[q] * dvz)) * rdamp[q];
        float nszz = (fszz[q] + (rlam[q] * dvx + rl2m[q] * dvz)) * rdamp[q];
        float nsxz = (fsxz[q] + rmu[q] * ((vxD - vxC) + (vzR - vzC))) * rdamp[q];
        if (q == qsrc) { nsxx += srcm * sval; nszz += srcm * sval; }
        fsxx[q] = nsxx; fszz[q] = nszz; fsxz[q] = nsxz;
        Lsxx[E * kPitch + lc] = nsxx;
        Lsxz[E * kPitch + lc] = nsxz;
        Lszz[E * kPitch + lc] = nszz;
    };

    __syncthreads();

    for (int t = 0; t < kNSTEPS; ++t) {
        const int rb = (t & 1) ^ 1;        // read buffer (step t-1 data)
        const int wb = t & 1;              // write buffer (step t data)

        // ---- pre-vel part 1: two interior rows per group (hide flag flight).
        //      Cross-group vertical values are stress(t-1) LDS mirrors,
        //      stable since the end-of-step barrier.
        if (active) {
            if (g == 0) {
                velRow(1, fsxz[0], fszz[2]);
                velRow(2, fsxz[1], fszz[3]);
            } else {
                velRow(0, Lsxz[3 * kPitch + lc], fszz[1]);   // sxz(t-1) row 3
                velRow(1, fsxz[0], fszz[2]);
            }
        }

        // ---- wait + ingest: each group spins ONLY its own flag, then
        //      issues its 8 halo loads ----
        float h_vx = 0, h_vz = 0, h_sxx = 0, h_s3 = 0, h_s4 = 0, h_s5 = 0;
        float h_sxxr = 0, h_sl = 0;
        if (t > 0) {
            if (g == 0 && hasTop) {
                while (ALD(ftopr) < t) {}
                if (active) {
                    // dir0 slots: vx[7],vz[7],sxx[7],szz[7],sxz[7],sxz[6]
                    const float* hb = hbase(rb, slab - 1, 0);
                    h_vx  = ALD(hb + ct);
                    h_vz  = ALD(hb + kNXP + ct);
                    h_sxx = ALD(hb + 2 * kNXP + ct);
                    h_s3  = ALD(hb + 3 * kNXP + ct);
                    h_s4  = ALD(hb + 4 * kNXP + ct);
                    h_s5  = ALD(hb + 5 * kNXP + ct);
                    if (ct < kNXP - 1) h_sxxr = ALD(hb + 2 * kNXP + ct + 1);
                    if (ct > 0)        h_sl   = ALD(hb + 4 * kNXP + ct - 1);
                }
            }
            if (g == 1 && hasBot) {
                while (ALD(fbotr) < t) {}
                if (active) {
                    // dir1 slots: vx[0],vz[0],sxx[0],sxz[0],szz[0],szz[1]
                    const float* hb = hbase(rb, slab, 1);
                    h_vx  = ALD(hb + ct);
                    h_vz  = ALD(hb + kNXP + ct);
                    h_sxx = ALD(hb + 2 * kNXP + ct);
                    h_s3  = ALD(hb + 3 * kNXP + ct);
                    h_s4  = ALD(hb + 4 * kNXP + ct);
                    h_s5  = ALD(hb + 5 * kNXP + ct);
                    if (ct < kNXP - 1) h_sxxr = ALD(hb + 2 * kNXP + ct + 1);
                    if (ct > 0)        h_sl   = ALD(hb + 3 * kNXP + ct - 1);
                }
            }
        }

        // ---- pre-vel part 2: one more interior row per group, no halo
        //      dependence — overlaps the halo-load flight ----
        if (active) {
            if (g == 0) velRow(3, fsxz[2], Lszz[4 * kPitch + lc]);  // szz(t-1) row 4
            else        velRow(2, fsxz[1], fszz[3]);
        }

        // ---- ghost + boundary-row velocity (round-0 formulas) ----
        float nvg_x = 0, nvg_z = 0;
        if (active) {
            if (g == 0) {
                nvg_x = (h_vx + dtrG * ((h_sxxr - h_sxx) + (h_s4 - h_s5))) * dmpG;
                nvg_z = (h_vz + dtrG * ((h_s4 - h_sl) + (fszz[0] - h_s3))) * dmpG;
                velRow(0, h_s4, fszz[1]);                    // row 0
            } else {
                nvg_x = (h_vx + dtrG * ((h_sxxr - h_sxx) + (h_s3 - fsxz[3]))) * dmpG;
                nvg_z = (h_vz + dtrG * ((h_s3 - h_sl) + (h_s5 - h_s4))) * dmpG;
                velRow(3, fsxz[2], h_s4);                    // row 7
            }
        }
        __syncthreads();   // vel LDS (incl. cross-group rows 3,4) -> stress

        // ---- stress(t): 4 serial rows per group, in parallel; publish ----
        if (active) {
            const float sval = stf[t] * kDT;
            if (g == 0) {
                stressRow(0, nvg_z,  fvx[1], sval);
                stressRow(1, fvz[0], fvx[2], sval);
                stressRow(2, fvz[1], fvx[3], sval);
                stressRow(3, fvz[2], Lvx[4 * kPitch + lc], sval);  // vx(t) row 4
            } else {
                stressRow(0, Lvz[3 * kPitch + lc], fvx[1], sval);  // vz(t) row 3
                stressRow(1, fvz[0], fvx[2], sval);
                stressRow(2, fvz[1], fvx[3], sval);
                stressRow(3, fvz[2], nvg_x, sval);
            }
            if (g == 0 && hasTop) {   // up (dir1): vx0,vz0,sxx0,sxz0,szz0,szz1
                float* hb = hbase(wb, slab - 1, 1);
                AST(hb + ct,            fvx[0]);
                AST(hb + kNXP + ct,     fvz[0]);
                AST(hb + 2 * kNXP + ct, fsxx[0]);
                AST(hb + 3 * kNXP + ct, fsxz[0]);
                AST(hb + 4 * kNXP + ct, fszz[0]);
                AST(hb + 5 * kNXP + ct, fszz[1]);
            }
            if (g == 1 && hasBot) {   // down (dir0): vx7,vz7,sxx7,szz7,sxz7,sxz6
                float* hb = hbase(wb, slab, 0);
                AST(hb + ct,            fvx[3]);
                AST(hb + kNXP + ct,     fvz[3]);
                AST(hb + 2 * kNXP + ct, fsxx[3]);
                AST(hb + 3 * kNXP + ct, fszz[3]);
                AST(hb + 4 * kNXP + ct, fsxz[3]);
                AST(hb + 5 * kNXP + ct, fsxz[2]);
            }
        }

        // ---- group-local LDS-vote flag publish: each publishing wave drains
        //      its OWN halo stores, bumps the group's monotonic counter; the
        //      8th wave stores the flag. Flag departs at the group's last
        //      drain — not after the global barrier. WAR induction unchanged
        //      (halo loads were consumed before the stress phase).
        if ((g == 0 && hasTop) || (g == 1 && hasBot)) {
            asm volatile("s_waitcnt vmcnt(0)" ::: "memory");
            if ((tid & 63) == 0) {
                const int old = atomicAdd(&cnt[g], 1);       // LDS, monotonic
                if (old == 8 * (t + 1) - 1) {
                    if (g == 0) AST(ftopw, t + 1);
                    else        AST(fbotw, t + 1);
                }
            }
        }
        LDS_BAR();   // stress LDS writes -> next pre-vel reads (no vmem drain)
    }

    // ---- loss: wave reduce -> block reduce (reuse LDS; trailing zero waves
    //      keep the sum bit-identical) -> tagged u64 publish; block 0 combines.
    for (int off = 32; off > 0; off >>= 1) rsum += __shfl_down(rsum, off, 64);
    __syncthreads();
    if ((tid & 63) == 0) L[tid >> 6] = rsum;
    __syncthreads();
    if (isRecBlock && tid == 0) {
        float tot = 0.0f;
#pragma unroll
        for (int w = 0; w < kThreads / 64; ++w) tot += L[w];
        const u64 word = ((u64)1 << 32) | (u64)__float_as_uint(tot);
        AST(&part[s], word);
    }
    if (blk == 0 && tid == 0) {
        u64 v0, v1;
        do { v0 = ALD(&part[0]); } while ((int)(v0 >> 32) < 1);  // poison negative
        do { v1 = ALD(&part[1]); } while ((int)(v1 >> 32) < 1);
        out[0] = 0.5f * (__uint_as_float((unsigned)v0) + __uint_as_float((unsigned)v1));
    }
}

extern "C" void kernel_launch(void* const* d_in, const int* in_sizes, int n_in,
                              void* d_out, int out_size, void* d_ws, size_t ws_size,
                              hipStream_t stream) {
    const float* Vp  = (const float*)d_in[0];
    const float* Vs  = (const float*)d_in[1];
    const float* Den = (const float*)d_in[2];
    const float* Stf = (const float*)d_in[3];
    // d_in[4] = Mask (all-ones; identity in forward value) -- unused
    const int* Shot_ids = (const int*)d_in[5];
    float* out = (float*)d_out;
    float* ws  = (float*)d_ws;

    // Single dispatch: r25 structure (45-link chain, 2 parallel row groups)
    // + group-local LDS-vote flag publish + split pre-vel. 92 blocks.
    fwi_sim_kernel<<<kBlocks, kThreads, 0, stream>>>(Vp, Vs, Den, Stf,
                                                     Shot_ids, ws, out);
}

// Round 11
// 557.024 us; speedup vs baseline: 1.0677x; 1.0677x over previous
//
#include <hip/hip_runtime.h>
#include <cmath>

typedef unsigned long long u64;

namespace {
constexpr int kNZ = 300, kNX = 400;
constexpr int kNPML = 32;
constexpr int kNZP = 364, kNXP = 464;        // padded physical grid
constexpr int kNSTEPS = 200, kNSHOTS = 2;
constexpr int kSRC_Z = 34, kREC_Z = 34;      // NPML + 2
constexpr float kDT = 0.001f;
constexpr float kINV_DX = 100.0f;            // 1/DX

// r27 = r25 (488us WIN: 8-row slabs, two parallel 512-thread row groups,
// 45-link chain) + ONE delta: per-group flag PREFETCH hoisted above pre-vel
// (the head-side flag RTT hides under the 3 interior vel rows; spin is
// skipped in the common lockstep case). r26's tail edits reverted (-55us).
// [resubmit: round-9 bench died on container infra, kernel never measured]
constexpr int kRS = 8;                        // rows per slab
constexpr int kQ  = 4;                        // rows per thread (per group)
constexpr int kNSLAB = 46;                    // 368 rows; 364..367 dead (zero moduli)
constexpr int kNB = kNSLAB - 1;               // 45 boundaries
constexpr int kBlocks = kNSHOTS * kNSLAB;     // 92 blocks, co-resident
constexpr int kThreads = 1024;                // 2 groups x 512 (464 cols active)
constexpr int kPitch = 468;                   // LDS row pitch (guard cols 0,465)
constexpr int kFStride = kRS * kPitch;        // 3744

// ws layout — NO init kernel needed (round-0 protocol, kNB=45):
//   [0, 16384)   : int flags[shot][b][dir] x32 pad. 0xAA poison = negative int
//                  => every signed `< t` wait is safe un-zeroed.
//   [16384, ...) : float halo[buf][shot][b][dir][slot(6)][464]
//   partials     : 2 x u64 {tag,float} at 8-aligned offset after halos.
constexpr int kFlagStride = 32;
constexpr int kHaloBase = 16384;
constexpr int kHaloCount = 2 * kNSHOTS * kNB * 2 * 6 * kNXP;   // 1,002,240
constexpr int kPartOff = kHaloBase + kHaloCount;               // even -> 8B aligned
}  // namespace

#define ALD(p)    __hip_atomic_load((p),       __ATOMIC_RELAXED, __HIP_MEMORY_SCOPE_AGENT)
#define AST(p, v) __hip_atomic_store((p), (v), __ATOMIC_RELAXED, __HIP_MEMORY_SCOPE_AGENT)

// Per-step schedule, protocol and FP expressions are r25's verbatim; the
// only change is the hoisted first flag sample.
__global__ __launch_bounds__(kThreads, 1) void fwi_sim_kernel(
    const float* __restrict__ Vp, const float* __restrict__ Vs,
    const float* __restrict__ Den, const float* __restrict__ Stf,
    const int* __restrict__ Shot_ids, float* __restrict__ ws,
    float* __restrict__ out) {
    __shared__ float L[5 * kFStride];   // 74,880 B (vx,vz,sxx,sxz,szz)
    float* Lvx  = L;
    float* Lvz  = L + kFStride;
    float* Lsxx = L + 2 * kFStride;
    float* Lsxz = L + 3 * kFStride;
    float* Lszz = L + 4 * kFStride;

    const int blk  = blockIdx.x;
    const int s    = blk / kNSLAB;
    const int slab = blk - s * kNSLAB;
    const int tid  = threadIdx.x;
    const int g    = tid >> 9;          // row-group: 0 = rows 0..3, 1 = rows 4..7
    const int ct   = tid & 511;         // column thread within group
    const bool active = ct < kNXP;
    const int lc = ct + 1;
    const int e0 = 4 * g;               // first row-in-slab of this group
    const int r0 = slab * kRS + e0;     // first global row of this thread

    int*   flags = (int*)ws;
    float* halo  = ws + kHaloBase;
    u64*   part  = (u64*)(ws + kPartOff);

    for (int q = tid; q < 5 * kFStride; q += kThreads) L[q] = 0.0f;

    auto modAt = [&](int i, int j, float& dtr_, float& dmp_, float& lam_,
                     float& mu_, float& l2m_) {
        dtr_ = dmp_ = lam_ = mu_ = l2m_ = 0.0f;
        if (i >= 0 && i < kNZP && j >= 0 && j < kNXP) {
            int iz = i - kNPML; iz = iz < 0 ? 0 : (iz > kNZ - 1 ? kNZ - 1 : iz);
            int jx = j - kNPML; jx = jx < 0 ? 0 : (jx > kNX - 1 ? kNX - 1 : jx);
            const float vp  = Vp[iz * kNX + jx];
            const float vs  = Vs[iz * kNX + jx];
            const float rho = Den[iz * kNX + jx];
            const float m = vs * vs * rho * 1e-6f;
            const float l = (vp * vp - 2.0f * vs * vs) * rho * 1e-6f;
            const float sc = kDT * kINV_DX;
            float dz = fmaxf((float)(kNPML - i), (float)(i - (kNZP - 1 - kNPML)));
            dz = fminf(fmaxf(dz, 0.0f), (float)kNPML) * (1.0f / kNPML);
            float dxx = fmaxf((float)(kNPML - j), (float)(j - (kNXP - 1 - kNPML)));
            dxx = fminf(fmaxf(dxx, 0.0f), (float)kNPML) * (1.0f / kNPML);
            dmp_ = expf(-0.1f * (dz * dz + dxx * dxx));
            dtr_ = kDT / rho * kINV_DX;
            lam_ = l * sc;
            mu_  = m * sc;
            l2m_ = (l + 2.0f * m) * sc;
        }
    };
    float rdtr[kQ], rdamp[kQ], rlam[kQ], rmu[kQ], rl2m[kQ];
    float dtrG = 0, dmpG = 0;            // g0: row slab*8-1 (top ghost); g1: +8 (bottom)
    if (active) {
#pragma unroll
        for (int q = 0; q < kQ; ++q)
            modAt(r0 + q, ct, rdtr[q], rdamp[q], rlam[q], rmu[q], rl2m[q]);
        float d0, d1, d2;
        if (g == 0) modAt(slab * kRS - 1,   ct, dtrG, dmpG, d0, d1, d2);
        else        modAt(slab * kRS + kRS, ct, dtrG, dmpG, d0, d1, d2);
    }

    const int id  = Shot_ids[s];
    const int sxp = kNPML + 20 + id * ((kNX - 40) / kNSHOTS);
    const float* stf = Stf + id * kNSTEPS;
    const int qsrc = kSRC_Z - r0;       // in [0,4) only for the owning group
    const int qrec = kREC_Z - r0;
    const bool isRecBlock = (kREC_Z >= slab * kRS && kREC_Z < slab * kRS + kRS);
    const float srcm = (active && ct == sxp) ? 1.0f : 0.0f;
    const float recm = (active && (unsigned)(ct - kNPML) < (unsigned)kNX) ? 1.0f : 0.0f;

    const bool hasTop = (slab > 0);
    const bool hasBot = (slab < kNSLAB - 1);
    int* ftopw = hasTop ? &flags[((s * kNB + (slab - 1)) * 2 + 1) * kFlagStride] : nullptr;
    int* fbotw = hasBot ? &flags[((s * kNB + slab) * 2 + 0) * kFlagStride] : nullptr;
    int* ftopr = hasTop ? &flags[((s * kNB + (slab - 1)) * 2 + 0) * kFlagStride] : nullptr;
    int* fbotr = hasBot ? &flags[((s * kNB + slab) * 2 + 1) * kFlagStride] : nullptr;
    auto hbase = [&](int buf, int b, int dir) {
        return halo + ((((buf * kNSHOTS + s) * kNB + b) * 2 + dir) * 6) * kNXP;
    };
    // this group's flag to poll (one per group; null if chain edge)
    int* fpoll = (g == 0) ? ftopr : fbotr;
    const bool hasPoll = (g == 0) ? hasTop : hasBot;

    float fvx[kQ]  = {}, fvz[kQ]  = {}, fsxx[kQ] = {}, fszz[kQ] = {}, fsxz[kQ] = {};
    float rsum = 0.0f;

    // velocity row update (round-0 expressions; vertical neighbors passed in)
    auto velRow = [&](int q, float sxz_up, float szz_dn) {
        const int E = e0 + q;
        const float sxxC = fsxx[q], sxzC = fsxz[q], szzC = fszz[q];
        const float sxxR = Lsxx[E * kPitch + lc + 1];
        const float sxzL = Lsxz[E * kPitch + lc - 1];
        const float nvx = (fvx[q] + rdtr[q] * ((sxxR - sxxC) + (sxzC - sxz_up))) * rdamp[q];
        const float nvz = (fvz[q] + rdtr[q] * ((sxzC - sxzL) + (szz_dn - szzC))) * rdamp[q];
        fvx[q] = nvx; fvz[q] = nvz;
        Lvx[E * kPitch + lc] = nvx; Lvz[E * kPitch + lc] = nvz;
        if (q == qrec) rsum += recm * nvx * nvx;
    };
    // stress row update (round-0 expressions)
    auto stressRow = [&](int q, float vzU, float vxD, float sval) {
        const int E = e0 + q;
        const float vxC = fvx[q], vzC = fvz[q];
        const float vxL = Lvx[E * kPitch + lc - 1];
        const float vzR = Lvz[E * kPitch + lc + 1];
        const float dvx = vxC - vxL;
        const float dvz = vzC - vzU;
        float nsxx = (fsxx[q] + (rl2m[q] * dvx + rlam[q] * dvz)) * rdamp[q];
        float nszz = (fszz[q] + (rlam[q] * dvx + rl2m[q] * dvz)) * rdamp[q];
        float nsxz = (fsxz[q] + rmu[q] * ((vxD - vxC) + (vzR - vzC))) * rdamp[q];
        if (q == qsrc) { nsxx += srcm * sval; nszz += srcm * sval; }
        fsxx[q] = nsxx; fszz[q] = nszz; fsxz[q] = nsxz;
        Lsxx[E * kPitch + lc] = nsxx;
        Lsxz[E * kPitch + lc] = nsxz;
        Lszz[E * kPitch + lc] = nszz;
    };

    __syncthreads();

    for (int t = 0; t < kNSTEPS; ++t) {
        const int rb = (t & 1) ^ 1;        // read buffer (step t-1 data)
        const int wb = t & 1;              // write buffer (step t data)

        // ---- r27 delta: PREFETCH this group's flag before pre-vel so its
        //      RTT hides under the 3 interior rows (one load, one flag).
        int fpre = 0x7fffffff;
        if (t > 0 && hasPoll) fpre = ALD(fpoll);

        // ---- pre-wait velocity: 3 interior rows per group, in parallel.
        //      Cross-group vertical values are stress(t-1) LDS mirrors,
        //      valid since the end-of-step barrier. Overlaps flag RTT.
        if (active) {
            if (g == 0) {
                velRow(1, fsxz[0], fszz[2]);
                velRow(2, fsxz[1], fszz[3]);
                velRow(3, fsxz[2], Lszz[4 * kPitch + lc]);   // szz(t-1) row 4
            } else {
                velRow(0, Lsxz[3 * kPitch + lc], fszz[1]);   // sxz(t-1) row 3
                velRow(1, fsxz[0], fszz[2]);
                velRow(2, fsxz[1], fszz[3]);
            }
        }

        // ---- wait + ingest: spin only if the prefetched sample was stale;
        //      then load this group's 8 halo words ----
        float h_vx = 0, h_vz = 0, h_sxx = 0, h_s3 = 0, h_s4 = 0, h_s5 = 0;
        float h_sxxr = 0, h_sl = 0;
        if (t > 0) {
            if (hasPoll && fpre < t) {
                while (ALD(fpoll) < t) {}
            }
            if (g == 0 && hasTop && active) {
                // dir0 slots: vx[7],vz[7],sxx[7],szz[7],sxz[7],sxz[6]
                const float* hb = hbase(rb, slab - 1, 0);
                h_vx  = ALD(hb + ct);
                h_vz  = ALD(hb + kNXP + ct);
                h_sxx = ALD(hb + 2 * kNXP + ct);
                h_s3  = ALD(hb + 3 * kNXP + ct);
                h_s4  = ALD(hb + 4 * kNXP + ct);
                h_s5  = ALD(hb + 5 * kNXP + ct);
                if (ct < kNXP - 1) h_sxxr = ALD(hb + 2 * kNXP + ct + 1);
                if (ct > 0)        h_sl   = ALD(hb + 4 * kNXP + ct - 1);
            }
            if (g == 1 && hasBot && active) {
                // dir1 slots: vx[0],vz[0],sxx[0],sxz[0],szz[0],szz[1]
                const float* hb = hbase(rb, slab, 1);
                h_vx  = ALD(hb + ct);
                h_vz  = ALD(hb + kNXP + ct);
                h_sxx = ALD(hb + 2 * kNXP + ct);
                h_s3  = ALD(hb + 3 * kNXP + ct);
                h_s4  = ALD(hb + 4 * kNXP + ct);
                h_s5  = ALD(hb + 5 * kNXP + ct);
                if (ct < kNXP - 1) h_sxxr = ALD(hb + 2 * kNXP + ct + 1);
                if (ct > 0)        h_sl   = ALD(hb + 3 * kNXP + ct - 1);
            }
        }

        // ---- ghost + boundary-row velocity (round-0 formulas) ----
        float nvg_x = 0, nvg_z = 0;
        if (active) {
            if (g == 0) {
                nvg_x = (h_vx + dtrG * ((h_sxxr - h_sxx) + (h_s4 - h_s5))) * dmpG;
                nvg_z = (h_vz + dtrG * ((h_s4 - h_sl) + (fszz[0] - h_s3))) * dmpG;
                velRow(0, h_s4, fszz[1]);                    // row 0
            } else {
                nvg_x = (h_vx + dtrG * ((h_sxxr - h_sxx) + (h_s3 - fsxz[3]))) * dmpG;
                nvg_z = (h_vz + dtrG * ((h_s3 - h_sl) + (h_s5 - h_s4))) * dmpG;
                velRow(3, fsxz[2], h_s4);                    // row 7
            }
        }
        __syncthreads();   // vel LDS (incl. cross-group rows 3,4) -> stress

        // ---- stress(t): 4 serial rows per group, in parallel; publish ----
        if (active) {
            const float sval = stf[t] * kDT;
            if (g == 0) {
                stressRow(0, nvg_z,  fvx[1], sval);
                stressRow(1, fvz[0], fvx[2], sval);
                stressRow(2, fvz[1], fvx[3], sval);
                stressRow(3, fvz[2], Lvx[4 * kPitch + lc], sval);  // vx(t) row 4
            } else {
                stressRow(0, Lvz[3 * kPitch + lc], fvx[1], sval);  // vz(t) row 3
                stressRow(1, fvz[0], fvx[2], sval);
                stressRow(2, fvz[1], fvx[3], sval);
                stressRow(3, fvz[2], nvg_x, sval);
            }
            if (g == 0 && hasTop) {   // up (dir1): vx0,vz0,sxx0,sxz0,szz0,szz1
                float* hb = hbase(wb, slab - 1, 1);
                AST(hb + ct,            fvx[0]);
                AST(hb + kNXP + ct,     fvz[0]);
                AST(hb + 2 * kNXP + ct, fsxx[0]);
                AST(hb + 3 * kNXP + ct, fsxz[0]);
                AST(hb + 4 * kNXP + ct, fszz[0]);
                AST(hb + 5 * kNXP + ct, fszz[1]);
            }
            if (g == 1 && hasBot) {   // down (dir0): vx7,vz7,sxx7,szz7,sxz7,sxz6
                float* hb = hbase(wb, slab, 0);
                AST(hb + ct,            fvx[3]);
                AST(hb + kNXP + ct,     fvz[3]);
                AST(hb + 2 * kNXP + ct, fsxx[3]);
                AST(hb + 3 * kNXP + ct, fszz[3]);
                AST(hb + 4 * kNXP + ct, fsxz[3]);
                AST(hb + 5 * kNXP + ct, fsxz[2]);
            }
        }
        __syncthreads();   // drains halo stores (vmcnt) before flag publish
        if (tid == 0 && hasTop) AST(ftopw, t + 1);
        if (tid == 1 && hasBot) AST(fbotw, t + 1);
    }

    // ---- loss: wave reduce -> block reduce (reuse LDS; trailing zero waves
    //      keep the sum bit-identical) -> tagged u64 publish; block 0 combines.
    for (int off = 32; off > 0; off >>= 1) rsum += __shfl_down(rsum, off, 64);
    __syncthreads();
    if ((tid & 63) == 0) L[tid >> 6] = rsum;
    __syncthreads();
    if (isRecBlock && tid == 0) {
        float tot = 0.0f;
#pragma unroll
        for (int w = 0; w < kThreads / 64; ++w) tot += L[w];
        const u64 word = ((u64)1 << 32) | (u64)__float_as_uint(tot);
        AST(&part[s], word);
    }
    if (blk == 0 && tid == 0) {
        u64 v0, v1;
        do { v0 = ALD(&part[0]); } while ((int)(v0 >> 32) < 1);  // poison negative
        do { v1 = ALD(&part[1]); } while ((int)(v1 >> 32) < 1);
        out[0] = 0.5f * (__uint_as_float((unsigned)v0) + __uint_as_float((unsigned)v1));
    }
}

extern "C" void kernel_launch(void* const* d_in, const int* in_sizes, int n_in,
                              void* d_out, int out_size, void* d_ws, size_t ws_size,
                              hipStream_t stream) {
    const float* Vp  = (const float*)d_in[0];
    const float* Vs  = (const float*)d_in[1];
    const float* Den = (const float*)d_in[2];
    const float* Stf = (const float*)d_in[3];
    // d_in[4] = Mask (all-ones; identity in forward value) -- unused
    const int* Shot_ids = (const int*)d_in[5];
    float* out = (float*)d_out;
    float* ws  = (float*)d_ws;

    // Single dispatch: r25 structure (45-link chain, 2 parallel row groups)
    // + per-group flag prefetch. 92 blocks co-resident.
    fwi_sim_kernel<<<kBlocks, kThreads, 0, stream>>>(Vp, Vs, Den, Stf,
                                                     Shot_ids, ws, out);
}

// Round 12
// 541.609 us; speedup vs baseline: 1.0981x; 1.0285x over previous
//
#include <hip/hip_runtime.h>
#include <cmath>

typedef unsigned long long u64;

namespace {
constexpr int kNZ = 300, kNX = 400;
constexpr int kNPML = 32;
constexpr int kNZP = 364, kNXP = 464;        // padded physical grid
constexpr int kNSTEPS = 200, kNSHOTS = 2;
constexpr int kSRC_Z = 34, kREC_Z = 34;      // NPML + 2
constexpr float kDT = 0.001f;
constexpr float kINV_DX = 100.0f;            // 1/DX

// r28 = r25 VERBATIM (best measured: 488 us kernel, absmax 0.0).
// 8-row slabs computed by TWO 512-thread row groups in parallel (4
// rows/thread serial), 45-link sync chain, halved halo traffic.
// r26 (tail LDS-vote, split pre-vel) and r27 (flag prefetch) both
// regressed and are reverted — the micro-surgery ledger is 0-for-7;
// only the structural chain-halving won.
constexpr int kRS = 8;                        // rows per slab
constexpr int kQ  = 4;                        // rows per thread (per group)
constexpr int kNSLAB = 46;                    // 368 rows; 364..367 dead (zero moduli)
constexpr int kNB = kNSLAB - 1;               // 45 boundaries
constexpr int kBlocks = kNSHOTS * kNSLAB;     // 92 blocks, co-resident
constexpr int kThreads = 1024;                // 2 groups x 512 (464 cols active)
constexpr int kPitch = 468;                   // LDS row pitch (guard cols 0,465)
constexpr int kFStride = kRS * kPitch;        // 3744

// ws layout — NO init kernel needed (round-0 protocol, kNB=45):
//   [0, 16384)   : int flags[shot][b][dir] x32 pad. 0xAA poison = negative int
//                  => every signed `< t` wait is safe un-zeroed.
//   [16384, ...) : float halo[buf][shot][b][dir][slot(6)][464]
//   partials     : 2 x u64 {tag,float} at 8-aligned offset after halos.
constexpr int kFlagStride = 32;
constexpr int kHaloBase = 16384;
constexpr int kHaloCount = 2 * kNSHOTS * kNB * 2 * 6 * kNXP;   // 1,002,240
constexpr int kPartOff = kHaloBase + kHaloCount;               // even -> 8B aligned
}  // namespace

#define ALD(p)    __hip_atomic_load((p),       __ATOMIC_RELAXED, __HIP_MEMORY_SCOPE_AGENT)
#define AST(p, v) __hip_atomic_store((p), (v), __ATOMIC_RELAXED, __HIP_MEMORY_SCOPE_AGENT)

// Per-step schedule, protocol and FP expressions are the round-0 kernel's,
// verbatim; the only change vs round-0 is the row->thread mapping (two
// groups) and the cross-group interface (rows 3<->4) routed through LDS
// mirrors (incl. the Lszz mirror), protected by the existing barriers.
__global__ __launch_bounds__(kThreads, 1) void fwi_sim_kernel(
    const float* __restrict__ Vp, const float* __restrict__ Vs,
    const float* __restrict__ Den, const float* __restrict__ Stf,
    const int* __restrict__ Shot_ids, float* __restrict__ ws,
    float* __restrict__ out) {
    __shared__ float L[5 * kFStride];   // 74,880 B (vx,vz,sxx,sxz,szz)
    float* Lvx  = L;
    float* Lvz  = L + kFStride;
    float* Lsxx = L + 2 * kFStride;
    float* Lsxz = L + 3 * kFStride;
    float* Lszz = L + 4 * kFStride;

    const int blk  = blockIdx.x;
    const int s    = blk / kNSLAB;
    const int slab = blk - s * kNSLAB;
    const int tid  = threadIdx.x;
    const int g    = tid >> 9;          // row-group: 0 = rows 0..3, 1 = rows 4..7
    const int ct   = tid & 511;         // column thread within group
    const bool active = ct < kNXP;
    const int lc = ct + 1;
    const int e0 = 4 * g;               // first row-in-slab of this group
    const int r0 = slab * kRS + e0;     // first global row of this thread

    int*   flags = (int*)ws;
    float* halo  = ws + kHaloBase;
    u64*   part  = (u64*)(ws + kPartOff);

    for (int q = tid; q < 5 * kFStride; q += kThreads) L[q] = 0.0f;

    auto modAt = [&](int i, int j, float& dtr_, float& dmp_, float& lam_,
                     float& mu_, float& l2m_) {
        dtr_ = dmp_ = lam_ = mu_ = l2m_ = 0.0f;
        if (i >= 0 && i < kNZP && j >= 0 && j < kNXP) {
            int iz = i - kNPML; iz = iz < 0 ? 0 : (iz > kNZ - 1 ? kNZ - 1 : iz);
            int jx = j - kNPML; jx = jx < 0 ? 0 : (jx > kNX - 1 ? kNX - 1 : jx);
            const float vp  = Vp[iz * kNX + jx];
            const float vs  = Vs[iz * kNX + jx];
            const float rho = Den[iz * kNX + jx];
            const float m = vs * vs * rho * 1e-6f;
            const float l = (vp * vp - 2.0f * vs * vs) * rho * 1e-6f;
            const float sc = kDT * kINV_DX;
            float dz = fmaxf((float)(kNPML - i), (float)(i - (kNZP - 1 - kNPML)));
            dz = fminf(fmaxf(dz, 0.0f), (float)kNPML) * (1.0f / kNPML);
            float dxx = fmaxf((float)(kNPML - j), (float)(j - (kNXP - 1 - kNPML)));
            dxx = fminf(fmaxf(dxx, 0.0f), (float)kNPML) * (1.0f / kNPML);
            dmp_ = expf(-0.1f * (dz * dz + dxx * dxx));
            dtr_ = kDT / rho * kINV_DX;
            lam_ = l * sc;
            mu_  = m * sc;
            l2m_ = (l + 2.0f * m) * sc;
        }
    };
    float rdtr[kQ], rdamp[kQ], rlam[kQ], rmu[kQ], rl2m[kQ];
    float dtrG = 0, dmpG = 0;            // g0: row slab*8-1 (top ghost); g1: +8 (bottom)
    if (active) {
#pragma unroll
        for (int q = 0; q < kQ; ++q)
            modAt(r0 + q, ct, rdtr[q], rdamp[q], rlam[q], rmu[q], rl2m[q]);
        float d0, d1, d2;
        if (g == 0) modAt(slab * kRS - 1,   ct, dtrG, dmpG, d0, d1, d2);
        else        modAt(slab * kRS + kRS, ct, dtrG, dmpG, d0, d1, d2);
    }

    const int id  = Shot_ids[s];
    const int sxp = kNPML + 20 + id * ((kNX - 40) / kNSHOTS);
    const float* stf = Stf + id * kNSTEPS;
    const int qsrc = kSRC_Z - r0;       // in [0,4) only for the owning group
    const int qrec = kREC_Z - r0;
    const bool isRecBlock = (kREC_Z >= slab * kRS && kREC_Z < slab * kRS + kRS);
    const float srcm = (active && ct == sxp) ? 1.0f : 0.0f;
    const float recm = (active && (unsigned)(ct - kNPML) < (unsigned)kNX) ? 1.0f : 0.0f;

    const bool hasTop = (slab > 0);
    const bool hasBot = (slab < kNSLAB - 1);
    int* ftopw = hasTop ? &flags[((s * kNB + (slab - 1)) * 2 + 1) * kFlagStride] : nullptr;
    int* fbotw = hasBot ? &flags[((s * kNB + slab) * 2 + 0) * kFlagStride] : nullptr;
    int* ftopr = hasTop ? &flags[((s * kNB + (slab - 1)) * 2 + 0) * kFlagStride] : nullptr;
    int* fbotr = hasBot ? &flags[((s * kNB + slab) * 2 + 1) * kFlagStride] : nullptr;
    auto hbase = [&](int buf, int b, int dir) {
        return halo + ((((buf * kNSHOTS + s) * kNB + b) * 2 + dir) * 6) * kNXP;
    };

    float fvx[kQ]  = {}, fvz[kQ]  = {}, fsxx[kQ] = {}, fszz[kQ] = {}, fsxz[kQ] = {};
    float rsum = 0.0f;

    // velocity row update (round-0 expressions; vertical neighbors passed in)
    auto velRow = [&](int q, float sxz_up, float szz_dn) {
        const int E = e0 + q;
        const float sxxC = fsxx[q], sxzC = fsxz[q], szzC = fszz[q];
        const float sxxR = Lsxx[E * kPitch + lc + 1];
        const float sxzL = Lsxz[E * kPitch + lc - 1];
        const float nvx = (fvx[q] + rdtr[q] * ((sxxR - sxxC) + (sxzC - sxz_up))) * rdamp[q];
        const float nvz = (fvz[q] + rdtr[q] * ((sxzC - sxzL) + (szz_dn - szzC))) * rdamp[q];
        fvx[q] = nvx; fvz[q] = nvz;
        Lvx[E * kPitch + lc] = nvx; Lvz[E * kPitch + lc] = nvz;
        if (q == qrec) rsum += recm * nvx * nvx;
    };
    // stress row update (round-0 expressions)
    auto stressRow = [&](int q, float vzU, float vxD, float sval) {
        const int E = e0 + q;
        const float vxC = fvx[q], vzC = fvz[q];
        const float vxL = Lvx[E * kPitch + lc - 1];
        const float vzR = Lvz[E * kPitch + lc + 1];
        const float dvx = vxC - vxL;
        const float dvz = vzC - vzU;
        float nsxx = (fsxx[q] + (rl2m[q] * dvx + rlam[q] * dvz)) * rdamp[q];
        float nszz = (fszz[q] + (rlam[q] * dvx + rl2m[q] * dvz)) * rdamp[q];
        float nsxz = (fsxz[q] + rmu[q] * ((vxD - vxC) + (vzR - vzC))) * rdamp[q];
        if (q == qsrc) { nsxx += srcm * sval; nszz += srcm * sval; }
        fsxx[q] = nsxx; fszz[q] = nszz; fsxz[q] = nsxz;
        Lsxx[E * kPitch + lc] = nsxx;
        Lsxz[E * kPitch + lc] = nsxz;
        Lszz[E * kPitch + lc] = nszz;
    };

    __syncthreads();

    for (int t = 0; t < kNSTEPS; ++t) {
        const int rb = (t & 1) ^ 1;        // read buffer (step t-1 data)
        const int wb = t & 1;              // write buffer (step t data)

        // ---- pre-wait velocity: 3 interior rows per group, in parallel.
        //      Cross-group vertical values are stress(t-1) LDS mirrors,
        //      valid since the end-of-step barrier. Overlaps flag RTT.
        if (active) {
            if (g == 0) {
                velRow(1, fsxz[0], fszz[2]);
                velRow(2, fsxz[1], fszz[3]);
                velRow(3, fsxz[2], Lszz[4 * kPitch + lc]);   // szz(t-1) row 4
            } else {
                velRow(0, Lsxz[3 * kPitch + lc], fszz[1]);   // sxz(t-1) row 3
                velRow(1, fsxz[0], fszz[2]);
                velRow(2, fsxz[1], fszz[3]);
            }
        }

        // ---- wait + ingest: each group spins ONLY its own flag (parallel
        //      detect across groups), then loads its 8 halo words ----
        float h_vx = 0, h_vz = 0, h_sxx = 0, h_s3 = 0, h_s4 = 0, h_s5 = 0;
        float h_sxxr = 0, h_sl = 0;
        if (t > 0) {
            if (g == 0 && hasTop) {
                while (ALD(ftopr) < t) {}
                if (active) {
                    // dir0 slots: vx[7],vz[7],sxx[7],szz[7],sxz[7],sxz[6]
                    const float* hb = hbase(rb, slab - 1, 0);
                    h_vx  = ALD(hb + ct);
                    h_vz  = ALD(hb + kNXP + ct);
                    h_sxx = ALD(hb + 2 * kNXP + ct);
                    h_s3  = ALD(hb + 3 * kNXP + ct);
                    h_s4  = ALD(hb + 4 * kNXP + ct);
                    h_s5  = ALD(hb + 5 * kNXP + ct);
                    if (ct < kNXP - 1) h_sxxr = ALD(hb + 2 * kNXP + ct + 1);
                    if (ct > 0)        h_sl   = ALD(hb + 4 * kNXP + ct - 1);
                }
            }
            if (g == 1 && hasBot) {
                while (ALD(fbotr) < t) {}
                if (active) {
                    // dir1 slots: vx[0],vz[0],sxx[0],sxz[0],szz[0],szz[1]
                    const float* hb = hbase(rb, slab, 1);
                    h_vx  = ALD(hb + ct);
                    h_vz  = ALD(hb + kNXP + ct);
                    h_sxx = ALD(hb + 2 * kNXP + ct);
                    h_s3  = ALD(hb + 3 * kNXP + ct);
                    h_s4  = ALD(hb + 4 * kNXP + ct);
                    h_s5  = ALD(hb + 5 * kNXP + ct);
                    if (ct < kNXP - 1) h_sxxr = ALD(hb + 2 * kNXP + ct + 1);
                    if (ct > 0)        h_sl   = ALD(hb + 3 * kNXP + ct - 1);
                }
            }
        }

        // ---- ghost + boundary-row velocity (round-0 formulas) ----
        float nvg_x = 0, nvg_z = 0;
        if (active) {
            if (g == 0) {
                nvg_x = (h_vx + dtrG * ((h_sxxr - h_sxx) + (h_s4 - h_s5))) * dmpG;
                nvg_z = (h_vz + dtrG * ((h_s4 - h_sl) + (fszz[0] - h_s3))) * dmpG;
                velRow(0, h_s4, fszz[1]);                    // row 0
            } else {
                nvg_x = (h_vx + dtrG * ((h_sxxr - h_sxx) + (h_s3 - fsxz[3]))) * dmpG;
                nvg_z = (h_vz + dtrG * ((h_s3 - h_sl) + (h_s5 - h_s4))) * dmpG;
                velRow(3, fsxz[2], h_s4);                    // row 7
            }
        }
        __syncthreads();   // vel LDS (incl. cross-group rows 3,4) -> stress

        // ---- stress(t): 4 serial rows per group, in parallel; publish ----
        if (active) {
            const float sval = stf[t] * kDT;
            if (g == 0) {
                stressRow(0, nvg_z,  fvx[1], sval);
                stressRow(1, fvz[0], fvx[2], sval);
                stressRow(2, fvz[1], fvx[3], sval);
                stressRow(3, fvz[2], Lvx[4 * kPitch + lc], sval);  // vx(t) row 4
            } else {
                stressRow(0, Lvz[3 * kPitch + lc], fvx[1], sval);  // vz(t) row 3
                stressRow(1, fvz[0], fvx[2], sval);
                stressRow(2, fvz[1], fvx[3], sval);
                stressRow(3, fvz[2], nvg_x, sval);
            }
            if (g == 0 && hasTop) {   // up (dir1): vx0,vz0,sxx0,sxz0,szz0,szz1
                float* hb = hbase(wb, slab - 1, 1);
                AST(hb + ct,            fvx[0]);
                AST(hb + kNXP + ct,     fvz[0]);
                AST(hb + 2 * kNXP + ct, fsxx[0]);
                AST(hb + 3 * kNXP + ct, fsxz[0]);
                AST(hb + 4 * kNXP + ct, fszz[0]);
                AST(hb + 5 * kNXP + ct, fszz[1]);
            }
            if (g == 1 && hasBot) {   // down (dir0): vx7,vz7,sxx7,szz7,sxz7,sxz6
                float* hb = hbase(wb, slab, 0);
                AST(hb + ct,            fvx[3]);
                AST(hb + kNXP + ct,     fvz[3]);
                AST(hb + 2 * kNXP + ct, fsxx[3]);
                AST(hb + 3 * kNXP + ct, fszz[3]);
                AST(hb + 4 * kNXP + ct, fsxz[3]);
                AST(hb + 5 * kNXP + ct, fsxz[2]);
            }
        }
        __syncthreads();   // drains halo stores (vmcnt) before flag publish
        if (tid == 0 && hasTop) AST(ftopw, t + 1);
        if (tid == 1 && hasBot) AST(fbotw, t + 1);
    }

    // ---- loss: wave reduce -> block reduce (reuse LDS; trailing zero waves
    //      keep the sum bit-identical) -> tagged u64 publish; block 0 combines.
    for (int off = 32; off > 0; off >>= 1) rsum += __shfl_down(rsum, off, 64);
    __syncthreads();
    if ((tid & 63) == 0) L[tid >> 6] = rsum;
    __syncthreads();
    if (isRecBlock && tid == 0) {
        float tot = 0.0f;
#pragma unroll
        for (int w = 0; w < kThreads / 64; ++w) tot += L[w];
        const u64 word = ((u64)1 << 32) | (u64)__float_as_uint(tot);
        AST(&part[s], word);
    }
    if (blk == 0 && tid == 0) {
        u64 v0, v1;
        do { v0 = ALD(&part[0]); } while ((int)(v0 >> 32) < 1);  // poison negative
        do { v1 = ALD(&part[1]); } while ((int)(v1 >> 32) < 1);
        out[0] = 0.5f * (__uint_as_float((unsigned)v0) + __uint_as_float((unsigned)v1));
    }
}

extern "C" void kernel_launch(void* const* d_in, const int* in_sizes, int n_in,
                              void* d_out, int out_size, void* d_ws, size_t ws_size,
                              hipStream_t stream) {
    const float* Vp  = (const float*)d_in[0];
    const float* Vs  = (const float*)d_in[1];
    const float* Den = (const float*)d_in[2];
    const float* Stf = (const float*)d_in[3];
    // d_in[4] = Mask (all-ones; identity in forward value) -- unused
    const int* Shot_ids = (const int*)d_in[5];
    float* out = (float*)d_out;
    float* ws  = (float*)d_ws;

    // Single dispatch: round-0 protocol, 8-row slabs via 2 parallel row
    // groups (1024 thr) -> 45-link chain, halved halo traffic, same serial
    // depth. 92 blocks co-resident.
    fwi_sim_kernel<<<kBlocks, kThreads, 0, stream>>>(Vp, Vs, Den, Stf,
                                                     Shot_ids, ws, out);
}